// Round 17
// baseline (86.437 us; speedup 1.0000x reference)
//
#include <hip/hip_runtime.h>

// Problem constants
#define B_   16
#define L_   6
#define H_   352
#define W_   704
#define HW_  (H_ * W_)          // 247808
#define NIMG (B_ * L_)          // 96
#define NMASK (NIMG * HW_)      // 23,789,568
#define THRESH 0.01f

// Work decomposition: wave = (img, strip, chunk)
#define NQ     176              // W/4 quads per row
#define NSTRIP 3                // strips of 62 output quads (last: 52)
#define NCHUNK 44
#define CH     8                // output rows per chunk (44*8 = 352)
#define ITEMS  (NIMG * NSTRIP * NCHUNK)   // 12672 waves
#define NBLK   (ITEMS / 4)                // 3168 blocks = 8 XCDs x 396

// OOB sentinel: sigmoid(-1e30) == 0 exactly -> zero-padded confidence map
#define OOBV  -1.0e30f

typedef float f4 __attribute__((ext_vector_type(4)));

// sigmoid via raw v_rcp_f32 (1-ulp) instead of IEEE divide
__device__ __forceinline__ f4 sig4max(f4 a, f4 b) {
    f4 c;
    c.x = __builtin_amdgcn_rcpf(1.f + __expf(-fmaxf(a.x, b.x)));
    c.y = __builtin_amdgcn_rcpf(1.f + __expf(-fmaxf(a.y, b.y)));
    c.z = __builtin_amdgcn_rcpf(1.f + __expf(-fmaxf(a.z, b.z)));
    c.w = __builtin_amdgcn_rcpf(1.f + __expf(-fmaxf(a.w, b.w)));
    return c;
}

template<bool HCHK>
__device__ __forceinline__ void load_pair(const float* __restrict__ xb,
                                          int h, int iq, bool colsafe,
                                          f4& a, f4& b) {
    bool ok = colsafe;
    if (HCHK) ok = ok && ((unsigned)h < (unsigned)H_);
    if (ok) {
        const size_t off = (size_t)h * W_ + 4 * iq;
        a = *(const f4*)(xb + off);
        b = *(const f4*)(xb + HW_ + off);
    } else {
        a = (f4){OOBV, OOBV, OOBV, OOBV};
        b = (f4){OOBV, OOBV, OOBV, OOBV};
    }
}

struct Wt { float u0,u1,u2,u3,u4, v0,v1,v2,v3,v4; };

template<bool HCHK>
__device__ __forceinline__ float run_chunk(
    const float* __restrict__ xb, const Wt w, int hA, int iq, bool colsafe,
    bool outlane, bool lead, bool ego, size_t obase,
    float* __restrict__ out_mask, float* __restrict__ sm_m1)
{
    float* __restrict__ sm = sm_m1 + 1;

    // Prologue: 6 row-pair loads issued back-to-back
    f4 c0, c1, c2, c3, q0a, q0b, q1a, q1b;
    {
        f4 a0, b0, a1, b1, a2, b2, a3, b3;
        load_pair<HCHK>(xb, hA - 2, iq, colsafe, a0, b0);
        load_pair<HCHK>(xb, hA - 1, iq, colsafe, a1, b1);
        load_pair<HCHK>(xb, hA,     iq, colsafe, a2, b2);
        load_pair<HCHK>(xb, hA + 1, iq, colsafe, a3, b3);
        load_pair<HCHK>(xb, hA + 2, iq, colsafe, q0a, q0b);
        load_pair<HCHK>(xb, hA + 3, iq, colsafe, q1a, q1b);
        c0 = sig4max(a0, b0);
        c1 = sig4max(a1, b1);
        c2 = sig4max(a2, b2);
        c3 = sig4max(a3, b3);
    }

    float cnt = 0.f;

    for (int r = 0; r < CH; ++r) {
        const int h = hA + r;

        // Prefetch raw row h+4 (depth-2), only rows this chunk needs
        f4 q2a, q2b;
        if (r < CH - 2) {
            load_pair<HCHK>(xb, h + 4, iq, colsafe, q2a, q2b);
        } else {
            q2a = (f4){OOBV, OOBV, OOBV, OOBV};
            q2b = (f4){OOBV, OOBV, OOBV, OOBV};
        }

        // Finish conf for row h+2 (its loads were issued 2 iterations ago)
        const f4 c4 = sig4max(q0a, q0b);

        // Vertical 5-tap (registers)
        f4 v;
        v.x = w.u0 * c0.x; v.y = w.u0 * c0.y; v.z = w.u0 * c0.z; v.w = w.u0 * c0.w;
        v.x = fmaf(w.u1, c1.x, v.x); v.y = fmaf(w.u1, c1.y, v.y);
        v.z = fmaf(w.u1, c1.z, v.z); v.w = fmaf(w.u1, c1.w, v.w);
        v.x = fmaf(w.u2, c2.x, v.x); v.y = fmaf(w.u2, c2.y, v.y);
        v.z = fmaf(w.u2, c2.z, v.z); v.w = fmaf(w.u2, c2.w, v.w);
        v.x = fmaf(w.u3, c3.x, v.x); v.y = fmaf(w.u3, c3.y, v.y);
        v.z = fmaf(w.u3, c3.z, v.z); v.w = fmaf(w.u3, c3.w, v.w);
        v.x = fmaf(w.u4, c4.x, v.x); v.y = fmaf(w.u4, c4.y, v.y);
        v.z = fmaf(w.u4, c4.z, v.z); v.w = fmaf(w.u4, c4.w, v.w);

        // Horizontal halo from neighbor lanes
        const float lz = __shfl_up(v.z, 1);
        const float lw = __shfl_up(v.w, 1);
        const float rx = __shfl_down(v.x, 1);
        const float ry = __shfl_down(v.y, 1);

        // Horizontal conv on ALL lanes (lane 0's o3 feeds lane 1's store)
        float o0, o1, o2, o3;
        {
            float a;
            a = w.v0 * lz;
            a = fmaf(w.v1, lw,  a); a = fmaf(w.v2, v.x, a);
            a = fmaf(w.v3, v.y, a); a = fmaf(w.v4, v.z, a);
            o0 = a;
            a = w.v0 * lw;
            a = fmaf(w.v1, v.x, a); a = fmaf(w.v2, v.y, a);
            a = fmaf(w.v3, v.z, a); a = fmaf(w.v4, v.w, a);
            o1 = a;
            a = w.v0 * v.x;
            a = fmaf(w.v1, v.y, a); a = fmaf(w.v2, v.z, a);
            a = fmaf(w.v3, v.w, a); a = fmaf(w.v4, rx,  a);
            o2 = a;
            a = w.v0 * v.y;
            a = fmaf(w.v1, v.z, a); a = fmaf(w.v2, v.w, a);
            a = fmaf(w.v3, rx,  a); a = fmaf(w.v4, ry,  a);
            o3 = a;
        }
        const float o3l = __shfl_up(o3, 1);   // left neighbor's col 4iq-1

        if (outlane) {
            const size_t idx = obase + (size_t)h * W_ + 4 * iq;

            // smoothed: shifted, 16B-aligned nontemporal f4 store
            if (lead) {
                f4 sv = { o3l, o0, o1, o2 };
                __builtin_nontemporal_store(sv, (f4*)(sm_m1 + idx));
            } else {  // iq == 0: cols 0..2 scalar (no col -1 write)
                __builtin_nontemporal_store(o0, sm + idx + 0);
                __builtin_nontemporal_store(o1, sm + idx + 1);
                __builtin_nontemporal_store(o2, sm + idx + 2);
            }
            if (iq == NQ - 1)                 // image last col (703)
                __builtin_nontemporal_store(o3, sm + idx + 3);

            // mask + rate (rate counted PRE-ego force)
            float m0 = (o0 > THRESH) ? 1.f : 0.f;
            float m1 = (o1 > THRESH) ? 1.f : 0.f;
            float m2 = (o2 > THRESH) ? 1.f : 0.f;
            float m3 = (o3 > THRESH) ? 1.f : 0.f;
            cnt += m0 + m1 + m2 + m3;
            f4 mv = ego ? (f4){1.f, 1.f, 1.f, 1.f} : (f4){m0, m1, m2, m3};
            __builtin_nontemporal_store(mv, (f4*)(out_mask + idx));
        }

        // Shift pipeline
        c0 = c1; c1 = c2; c2 = c3; c3 = c4;
        q0a = q1a; q0b = q1b; q1a = q2a; q1b = q2b;
    }
    return cnt;
}

__global__ __launch_bounds__(256, 4) void comm_fused_v13(
    const float* __restrict__ x,      // (B,L,2,H,W)
    const float* __restrict__ gw,     // (1,1,5,5)
    float* __restrict__ out_mask,     // (B*L,1,H,W)
    float* __restrict__ partials,     // d_ws: ITEMS floats, one per wave
    float* __restrict__ sm_m1)        // out + NMASK (= smoothed base - 1, 16B-aligned)
{
    const int wave = threadIdx.x >> 6;
    const int lane = threadIdx.x & 63;

    // XCD-aware bijective swizzle (NBLK = 3168 = 8*396): contiguous 396-block
    // range per XCD -> vertically adjacent chunks share halo rows in one L2.
    const int bid  = blockIdx.x;
    const int sw   = (bid & 7) * (NBLK / 8) + (bid >> 3);
    const int item = sw * 4 + wave;

    const int img   = item / (NSTRIP * NCHUNK);
    const int rem   = item % (NSTRIP * NCHUNK);
    const int strip = rem / NCHUNK;
    const int chunk = rem % NCHUNK;

    const int hA = chunk * CH;
    const int iq = strip * 62 - 1 + lane;
    const bool colsafe = (unsigned)iq < (unsigned)NQ;      // loop-invariant
    const bool outlane = (lane >= 1) && (lane <= 62) && colsafe;
    const bool lead    = outlane && (iq > 0);
    const bool ego     = (img % L_) == 0;

    const float* xb = x + (size_t)img * (2 * HW_);
    const size_t obase = (size_t)img * HW_;

    // Exact separable weights: g2d[i][j] == u[i] * hv[j]
    Wt w;
    {
        const float g12 = gw[12];
        w.u0 = gw[2];  w.u1 = gw[7];  w.u2 = gw[12]; w.u3 = gw[17]; w.u4 = gw[22];
        w.v0 = gw[10] / g12; w.v1 = gw[11] / g12; w.v2 = gw[12] / g12;
        w.v3 = gw[13] / g12; w.v4 = gw[14] / g12;
    }

    // Interior chunks (1..NCHUNK-2) never touch OOB rows -> skip the h check.
    float cnt;
    if (chunk == 0 || chunk == NCHUNK - 1)
        cnt = run_chunk<true >(xb, w, hA, iq, colsafe, outlane, lead, ego, obase, out_mask, sm_m1);
    else
        cnt = run_chunk<false>(xb, w, hA, iq, colsafe, outlane, lead, ego, obase, out_mask, sm_m1);

    // Per-wave reduce -> unique d_ws slot. NO atomics anywhere.
    #pragma unroll
    for (int off = 32; off >= 1; off >>= 1)
        cnt += __shfl_down(cnt, off);
    if (lane == 0)
        partials[item] = cnt;
}

// Tiny second kernel: reduce ITEMS partials -> rate scalar (single block)
__global__ __launch_bounds__(256) void comm_rate_reduce(
    const float* __restrict__ partials, float* __restrict__ rate)
{
    float s = 0.f;
    for (int i = threadIdx.x; i < ITEMS; i += 256)
        s += partials[i];
    #pragma unroll
    for (int off = 32; off >= 1; off >>= 1)
        s += __shfl_down(s, off);
    __shared__ float ws[4];
    if ((threadIdx.x & 63) == 0) ws[threadIdx.x >> 6] = s;
    __syncthreads();
    if (threadIdx.x == 0)
        rate[0] = (ws[0] + ws[1] + ws[2] + ws[3]) * (1.f / (float)NMASK);
}

extern "C" void kernel_launch(void* const* d_in, const int* in_sizes, int n_in,
                              void* d_out, int out_size, void* d_ws, size_t ws_size,
                              hipStream_t stream) {
    const float* x  = (const float*)d_in[0];
    const float* gw = (const float*)d_in[1];
    float* out      = (float*)d_out;

    float* mask_out = out;               // 23,789,568
    float* rate_out = out + NMASK;       // 1
    float* sm_m1    = out + NMASK;       // smoothed base - 1 (16B-aligned)
    float* partials = (float*)d_ws;      // ITEMS floats of scratch

    // rate slot (= sm_m1[0]) is written ONLY by comm_rate_reduce; smoothed
    // stores never touch it (f4 stores start at idx>=4; scalar path >= sm_m1+1).
    dim3 grid(NBLK, 1, 1);               // 3168 blocks x 256 threads = 12672 waves
    dim3 block(256, 1, 1);
    comm_fused_v13<<<grid, block, 0, stream>>>(x, gw, mask_out, partials, sm_m1);
    comm_rate_reduce<<<1, 256, 0, stream>>>(partials, rate_out);
}

// Round 18
// 74.810 us; speedup vs baseline: 1.1554x; 1.1554x over previous
//
#include <hip/hip_runtime.h>

// Problem constants
#define B_   16
#define L_   6
#define H_   352
#define W_   704
#define HW_  (H_ * W_)          // 247808
#define NIMG (B_ * L_)          // 96
#define NMASK (NIMG * HW_)      // 23,789,568
#define THRESH 0.01f

// Work decomposition: wave = (img, strip, chunk)
#define NQ     176              // W/4 quads per row
#define NSTRIP 3                // strips of 62 output quads (last: 52)
#define NCHUNK 16
#define CH     22               // output rows per chunk (16*22 = 352)
#define ITEMS  (NIMG * NSTRIP * NCHUNK)   // 4608 waves
#define NBLK   (ITEMS / 4)                // 1152 blocks = 8 XCDs x 144

// OOB sentinel: sigmoid(-1e30) == 0 exactly -> zero-padded confidence map
#define OOBV  -1.0e30f

typedef float f4 __attribute__((ext_vector_type(4)));

// sigmoid via raw v_rcp_f32 (1-ulp) instead of IEEE divide
__device__ __forceinline__ f4 sig4max(f4 a, f4 b) {
    f4 c;
    c.x = __builtin_amdgcn_rcpf(1.f + __expf(-fmaxf(a.x, b.x)));
    c.y = __builtin_amdgcn_rcpf(1.f + __expf(-fmaxf(a.y, b.y)));
    c.z = __builtin_amdgcn_rcpf(1.f + __expf(-fmaxf(a.z, b.z)));
    c.w = __builtin_amdgcn_rcpf(1.f + __expf(-fmaxf(a.w, b.w)));
    return c;
}

template<bool HCHK>
__device__ __forceinline__ void load_pair(const float* __restrict__ xb,
                                          int h, int iq, bool colsafe,
                                          f4& a, f4& b) {
    bool ok = colsafe;
    if (HCHK) ok = ok && ((unsigned)h < (unsigned)H_);
    if (ok) {
        const size_t off = (size_t)h * W_ + 4 * iq;
        a = *(const f4*)(xb + off);
        b = *(const f4*)(xb + HW_ + off);
    } else {
        a = (f4){OOBV, OOBV, OOBV, OOBV};
        b = (f4){OOBV, OOBV, OOBV, OOBV};
    }
}

struct Wt { float u0,u1,u2,u3,u4, v0,v1,v2,v3,v4; };

template<bool HCHK>
__device__ __forceinline__ float run_chunk(
    const float* __restrict__ xb, const Wt w, int hA, int iq, bool colsafe,
    bool outlane, bool lead, bool ego, size_t obase,
    float* __restrict__ out_mask, float* __restrict__ sm_m1)
{
    float* __restrict__ sm = sm_m1 + 1;

    // Prologue: 6 row-pair loads issued back-to-back
    f4 c0, c1, c2, c3, q0a, q0b, q1a, q1b;
    {
        f4 a0, b0, a1, b1, a2, b2, a3, b3;
        load_pair<HCHK>(xb, hA - 2, iq, colsafe, a0, b0);
        load_pair<HCHK>(xb, hA - 1, iq, colsafe, a1, b1);
        load_pair<HCHK>(xb, hA,     iq, colsafe, a2, b2);
        load_pair<HCHK>(xb, hA + 1, iq, colsafe, a3, b3);
        load_pair<HCHK>(xb, hA + 2, iq, colsafe, q0a, q0b);
        load_pair<HCHK>(xb, hA + 3, iq, colsafe, q1a, q1b);
        c0 = sig4max(a0, b0);
        c1 = sig4max(a1, b1);
        c2 = sig4max(a2, b2);
        c3 = sig4max(a3, b3);
    }

    float cnt = 0.f;

    for (int r = 0; r < CH; ++r) {
        const int h = hA + r;

        // Prefetch raw row h+4 (depth-2), only rows this chunk needs
        f4 q2a, q2b;
        if (r < CH - 2) {
            load_pair<HCHK>(xb, h + 4, iq, colsafe, q2a, q2b);
        } else {
            q2a = (f4){OOBV, OOBV, OOBV, OOBV};
            q2b = (f4){OOBV, OOBV, OOBV, OOBV};
        }

        // Finish conf for row h+2 (its loads were issued 2 iterations ago)
        const f4 c4 = sig4max(q0a, q0b);

        // Vertical 5-tap (registers)
        f4 v;
        v.x = w.u0 * c0.x; v.y = w.u0 * c0.y; v.z = w.u0 * c0.z; v.w = w.u0 * c0.w;
        v.x = fmaf(w.u1, c1.x, v.x); v.y = fmaf(w.u1, c1.y, v.y);
        v.z = fmaf(w.u1, c1.z, v.z); v.w = fmaf(w.u1, c1.w, v.w);
        v.x = fmaf(w.u2, c2.x, v.x); v.y = fmaf(w.u2, c2.y, v.y);
        v.z = fmaf(w.u2, c2.z, v.z); v.w = fmaf(w.u2, c2.w, v.w);
        v.x = fmaf(w.u3, c3.x, v.x); v.y = fmaf(w.u3, c3.y, v.y);
        v.z = fmaf(w.u3, c3.z, v.z); v.w = fmaf(w.u3, c3.w, v.w);
        v.x = fmaf(w.u4, c4.x, v.x); v.y = fmaf(w.u4, c4.y, v.y);
        v.z = fmaf(w.u4, c4.z, v.z); v.w = fmaf(w.u4, c4.w, v.w);

        // Horizontal halo from neighbor lanes
        const float lz = __shfl_up(v.z, 1);
        const float lw = __shfl_up(v.w, 1);
        const float rx = __shfl_down(v.x, 1);
        const float ry = __shfl_down(v.y, 1);

        // Horizontal conv on ALL lanes (lane 0's o3 feeds lane 1's store)
        float o0, o1, o2, o3;
        {
            float a;
            a = w.v0 * lz;
            a = fmaf(w.v1, lw,  a); a = fmaf(w.v2, v.x, a);
            a = fmaf(w.v3, v.y, a); a = fmaf(w.v4, v.z, a);
            o0 = a;
            a = w.v0 * lw;
            a = fmaf(w.v1, v.x, a); a = fmaf(w.v2, v.y, a);
            a = fmaf(w.v3, v.z, a); a = fmaf(w.v4, v.w, a);
            o1 = a;
            a = w.v0 * v.x;
            a = fmaf(w.v1, v.y, a); a = fmaf(w.v2, v.z, a);
            a = fmaf(w.v3, v.w, a); a = fmaf(w.v4, rx,  a);
            o2 = a;
            a = w.v0 * v.y;
            a = fmaf(w.v1, v.z, a); a = fmaf(w.v2, v.w, a);
            a = fmaf(w.v3, rx,  a); a = fmaf(w.v4, ry,  a);
            o3 = a;
        }
        const float o3l = __shfl_up(o3, 1);   // left neighbor's col 4iq-1

        if (outlane) {
            const size_t idx = obase + (size_t)h * W_ + 4 * iq;

            // smoothed: shifted, 16B-aligned nontemporal f4 store
            if (lead) {
                f4 sv = { o3l, o0, o1, o2 };
                __builtin_nontemporal_store(sv, (f4*)(sm_m1 + idx));
            } else {  // iq == 0: cols 0..2 scalar (no col -1 write)
                __builtin_nontemporal_store(o0, sm + idx + 0);
                __builtin_nontemporal_store(o1, sm + idx + 1);
                __builtin_nontemporal_store(o2, sm + idx + 2);
            }
            if (iq == NQ - 1)                 // image last col (703)
                __builtin_nontemporal_store(o3, sm + idx + 3);

            // mask + rate (rate counted PRE-ego force)
            float m0 = (o0 > THRESH) ? 1.f : 0.f;
            float m1 = (o1 > THRESH) ? 1.f : 0.f;
            float m2 = (o2 > THRESH) ? 1.f : 0.f;
            float m3 = (o3 > THRESH) ? 1.f : 0.f;
            cnt += m0 + m1 + m2 + m3;
            f4 mv = ego ? (f4){1.f, 1.f, 1.f, 1.f} : (f4){m0, m1, m2, m3};
            __builtin_nontemporal_store(mv, (f4*)(out_mask + idx));
        }

        // Shift pipeline
        c0 = c1; c1 = c2; c2 = c3; c3 = c4;
        q0a = q1a; q0b = q1b; q1a = q2a; q1b = q2b;
    }
    return cnt;
}

__global__ __launch_bounds__(256, 4) void comm_fused_v14(
    const float* __restrict__ x,      // (B,L,2,H,W)
    const float* __restrict__ gw,     // (1,1,5,5)
    float* __restrict__ out_mask,     // (B*L,1,H,W)
    float* __restrict__ partials,     // d_ws: ITEMS floats, one per wave
    float* __restrict__ sm_m1)        // out + NMASK (= smoothed base - 1, 16B-aligned)
{
    const int wave = threadIdx.x >> 6;
    const int lane = threadIdx.x & 63;

    // XCD-aware bijective swizzle (NBLK = 1152 = 8*144): contiguous 144-block
    // range per XCD -> vertically adjacent chunks share halo rows in one L2.
    const int bid  = blockIdx.x;
    const int sw   = (bid & 7) * (NBLK / 8) + (bid >> 3);
    const int item = sw * 4 + wave;

    const int img   = item / (NSTRIP * NCHUNK);
    const int rem   = item % (NSTRIP * NCHUNK);
    const int strip = rem / NCHUNK;
    const int chunk = rem % NCHUNK;

    const int hA = chunk * CH;
    const int iq = strip * 62 - 1 + lane;
    const bool colsafe = (unsigned)iq < (unsigned)NQ;      // loop-invariant
    const bool outlane = (lane >= 1) && (lane <= 62) && colsafe;
    const bool lead    = outlane && (iq > 0);
    const bool ego     = (img % L_) == 0;

    const float* xb = x + (size_t)img * (2 * HW_);
    const size_t obase = (size_t)img * HW_;

    // Exact separable weights: g2d[i][j] == u[i] * hv[j]
    Wt w;
    {
        const float g12 = gw[12];
        w.u0 = gw[2];  w.u1 = gw[7];  w.u2 = gw[12]; w.u3 = gw[17]; w.u4 = gw[22];
        w.v0 = gw[10] / g12; w.v1 = gw[11] / g12; w.v2 = gw[12] / g12;
        w.v3 = gw[13] / g12; w.v4 = gw[14] / g12;
    }

    // Interior chunks (1..NCHUNK-2) never touch OOB rows -> skip the h check.
    float cnt;
    if (chunk == 0 || chunk == NCHUNK - 1)
        cnt = run_chunk<true >(xb, w, hA, iq, colsafe, outlane, lead, ego, obase, out_mask, sm_m1);
    else
        cnt = run_chunk<false>(xb, w, hA, iq, colsafe, outlane, lead, ego, obase, out_mask, sm_m1);

    // Per-wave reduce -> unique d_ws slot. NO atomics anywhere.
    #pragma unroll
    for (int off = 32; off >= 1; off >>= 1)
        cnt += __shfl_down(cnt, off);
    if (lane == 0)
        partials[item] = cnt;
}

// Tiny second kernel: reduce ITEMS partials -> rate scalar (single block)
__global__ __launch_bounds__(256) void comm_rate_reduce(
    const float* __restrict__ partials, float* __restrict__ rate)
{
    float s = 0.f;
    for (int i = threadIdx.x; i < ITEMS; i += 256)
        s += partials[i];
    #pragma unroll
    for (int off = 32; off >= 1; off >>= 1)
        s += __shfl_down(s, off);
    __shared__ float ws[4];
    if ((threadIdx.x & 63) == 0) ws[threadIdx.x >> 6] = s;
    __syncthreads();
    if (threadIdx.x == 0)
        rate[0] = (ws[0] + ws[1] + ws[2] + ws[3]) * (1.f / (float)NMASK);
}

extern "C" void kernel_launch(void* const* d_in, const int* in_sizes, int n_in,
                              void* d_out, int out_size, void* d_ws, size_t ws_size,
                              hipStream_t stream) {
    const float* x  = (const float*)d_in[0];
    const float* gw = (const float*)d_in[1];
    float* out      = (float*)d_out;

    float* mask_out = out;               // 23,789,568
    float* rate_out = out + NMASK;       // 1
    float* sm_m1    = out + NMASK;       // smoothed base - 1 (16B-aligned)
    float* partials = (float*)d_ws;      // ITEMS floats of scratch

    // rate slot (= sm_m1[0]) is written ONLY by comm_rate_reduce; smoothed
    // stores never touch it (f4 stores start at idx>=4; scalar path >= sm_m1+1).
    dim3 grid(NBLK, 1, 1);               // 1152 blocks x 256 threads = 4608 waves
    dim3 block(256, 1, 1);
    comm_fused_v14<<<grid, block, 0, stream>>>(x, gw, mask_out, partials, sm_m1);
    comm_rate_reduce<<<1, 256, 0, stream>>>(partials, rate_out);
}

// Round 19
// 74.035 us; speedup vs baseline: 1.1675x; 1.0105x over previous
//
#include <hip/hip_runtime.h>

// Problem constants
#define B_   16
#define L_   6
#define H_   352
#define W_   704
#define HW_  (H_ * W_)          // 247808
#define NIMG (B_ * L_)          // 96
#define NMASK (NIMG * HW_)      // 23,789,568
#define THRESH 0.01f

// Work decomposition: wave = (img, strip, chunk)
#define NQ     176              // W/4 quads per row
#define NSTRIP 3                // strips of 62 output quads (last: 52)
#define NCHUNK 11
#define CH     32               // output rows per chunk (11*32 = 352)
#define ITEMS  (NIMG * NSTRIP * NCHUNK)   // 3168 waves
#define NBLK   (ITEMS / 4)                // 792 blocks = 8 XCDs x 99

// OOB sentinel: sigmoid(-1e30) == 0 exactly -> zero-padded confidence map
#define OOBV  -1.0e30f

typedef float f4 __attribute__((ext_vector_type(4)));

// sigmoid via raw v_rcp_f32 (1-ulp) instead of IEEE divide
__device__ __forceinline__ f4 sig4max(f4 a, f4 b) {
    f4 c;
    c.x = __builtin_amdgcn_rcpf(1.f + __expf(-fmaxf(a.x, b.x)));
    c.y = __builtin_amdgcn_rcpf(1.f + __expf(-fmaxf(a.y, b.y)));
    c.z = __builtin_amdgcn_rcpf(1.f + __expf(-fmaxf(a.z, b.z)));
    c.w = __builtin_amdgcn_rcpf(1.f + __expf(-fmaxf(a.w, b.w)));
    return c;
}

template<bool HCHK>
__device__ __forceinline__ void load_pair(const float* __restrict__ xb,
                                          int h, int iq, bool colsafe,
                                          f4& a, f4& b) {
    bool ok = colsafe;
    if (HCHK) ok = ok && ((unsigned)h < (unsigned)H_);
    if (ok) {
        const size_t off = (size_t)h * W_ + 4 * iq;
        a = *(const f4*)(xb + off);
        b = *(const f4*)(xb + HW_ + off);
    } else {
        a = (f4){OOBV, OOBV, OOBV, OOBV};
        b = (f4){OOBV, OOBV, OOBV, OOBV};
    }
}

struct Wt { float u0,u1,u2,u3,u4, v0,v1,v2,v3,v4; };

template<bool HCHK>
__device__ __forceinline__ float run_chunk(
    const float* __restrict__ xb, const Wt w, int hA, int iq, bool colsafe,
    bool outlane, bool lead, bool ego, size_t obase,
    float* __restrict__ out_mask, float* __restrict__ sm_m1)
{
    float* __restrict__ sm = sm_m1 + 1;

    // Prologue: 6 row-pair loads issued back-to-back
    f4 c0, c1, c2, c3, q0a, q0b, q1a, q1b;
    {
        f4 a0, b0, a1, b1, a2, b2, a3, b3;
        load_pair<HCHK>(xb, hA - 2, iq, colsafe, a0, b0);
        load_pair<HCHK>(xb, hA - 1, iq, colsafe, a1, b1);
        load_pair<HCHK>(xb, hA,     iq, colsafe, a2, b2);
        load_pair<HCHK>(xb, hA + 1, iq, colsafe, a3, b3);
        load_pair<HCHK>(xb, hA + 2, iq, colsafe, q0a, q0b);
        load_pair<HCHK>(xb, hA + 3, iq, colsafe, q1a, q1b);
        c0 = sig4max(a0, b0);
        c1 = sig4max(a1, b1);
        c2 = sig4max(a2, b2);
        c3 = sig4max(a3, b3);
    }

    float cnt = 0.f;

    for (int r = 0; r < CH; ++r) {
        const int h = hA + r;

        // Prefetch raw row h+4 (depth-2), only rows this chunk needs
        f4 q2a, q2b;
        if (r < CH - 2) {
            load_pair<HCHK>(xb, h + 4, iq, colsafe, q2a, q2b);
        } else {
            q2a = (f4){OOBV, OOBV, OOBV, OOBV};
            q2b = (f4){OOBV, OOBV, OOBV, OOBV};
        }

        // Finish conf for row h+2 (its loads were issued 2 iterations ago)
        const f4 c4 = sig4max(q0a, q0b);

        // Vertical 5-tap (registers)
        f4 v;
        v.x = w.u0 * c0.x; v.y = w.u0 * c0.y; v.z = w.u0 * c0.z; v.w = w.u0 * c0.w;
        v.x = fmaf(w.u1, c1.x, v.x); v.y = fmaf(w.u1, c1.y, v.y);
        v.z = fmaf(w.u1, c1.z, v.z); v.w = fmaf(w.u1, c1.w, v.w);
        v.x = fmaf(w.u2, c2.x, v.x); v.y = fmaf(w.u2, c2.y, v.y);
        v.z = fmaf(w.u2, c2.z, v.z); v.w = fmaf(w.u2, c2.w, v.w);
        v.x = fmaf(w.u3, c3.x, v.x); v.y = fmaf(w.u3, c3.y, v.y);
        v.z = fmaf(w.u3, c3.z, v.z); v.w = fmaf(w.u3, c3.w, v.w);
        v.x = fmaf(w.u4, c4.x, v.x); v.y = fmaf(w.u4, c4.y, v.y);
        v.z = fmaf(w.u4, c4.z, v.z); v.w = fmaf(w.u4, c4.w, v.w);

        // Horizontal halo from neighbor lanes
        const float lz = __shfl_up(v.z, 1);
        const float lw = __shfl_up(v.w, 1);
        const float rx = __shfl_down(v.x, 1);
        const float ry = __shfl_down(v.y, 1);

        // Horizontal conv on ALL lanes (lane 0's o3 feeds lane 1's store)
        float o0, o1, o2, o3;
        {
            float a;
            a = w.v0 * lz;
            a = fmaf(w.v1, lw,  a); a = fmaf(w.v2, v.x, a);
            a = fmaf(w.v3, v.y, a); a = fmaf(w.v4, v.z, a);
            o0 = a;
            a = w.v0 * lw;
            a = fmaf(w.v1, v.x, a); a = fmaf(w.v2, v.y, a);
            a = fmaf(w.v3, v.z, a); a = fmaf(w.v4, v.w, a);
            o1 = a;
            a = w.v0 * v.x;
            a = fmaf(w.v1, v.y, a); a = fmaf(w.v2, v.z, a);
            a = fmaf(w.v3, v.w, a); a = fmaf(w.v4, rx,  a);
            o2 = a;
            a = w.v0 * v.y;
            a = fmaf(w.v1, v.z, a); a = fmaf(w.v2, v.w, a);
            a = fmaf(w.v3, rx,  a); a = fmaf(w.v4, ry,  a);
            o3 = a;
        }
        const float o3l = __shfl_up(o3, 1);   // left neighbor's col 4iq-1

        if (outlane) {
            const size_t idx = obase + (size_t)h * W_ + 4 * iq;

            // smoothed: shifted, 16B-aligned nontemporal f4 store
            if (lead) {
                f4 sv = { o3l, o0, o1, o2 };
                __builtin_nontemporal_store(sv, (f4*)(sm_m1 + idx));
            } else {  // iq == 0: cols 0..2 scalar (no col -1 write)
                __builtin_nontemporal_store(o0, sm + idx + 0);
                __builtin_nontemporal_store(o1, sm + idx + 1);
                __builtin_nontemporal_store(o2, sm + idx + 2);
            }
            if (iq == NQ - 1)                 // image last col (703)
                __builtin_nontemporal_store(o3, sm + idx + 3);

            // mask + rate (rate counted PRE-ego force)
            float m0 = (o0 > THRESH) ? 1.f : 0.f;
            float m1 = (o1 > THRESH) ? 1.f : 0.f;
            float m2 = (o2 > THRESH) ? 1.f : 0.f;
            float m3 = (o3 > THRESH) ? 1.f : 0.f;
            cnt += m0 + m1 + m2 + m3;
            f4 mv = ego ? (f4){1.f, 1.f, 1.f, 1.f} : (f4){m0, m1, m2, m3};
            __builtin_nontemporal_store(mv, (f4*)(out_mask + idx));
        }

        // Shift pipeline
        c0 = c1; c1 = c2; c2 = c3; c3 = c4;
        q0a = q1a; q0b = q1b; q1a = q2a; q1b = q2b;
    }
    return cnt;
}

__global__ __launch_bounds__(256, 4) void comm_fused_v15(
    const float* __restrict__ x,      // (B,L,2,H,W)
    const float* __restrict__ gw,     // (1,1,5,5)
    float* __restrict__ out_mask,     // (B*L,1,H,W)
    float* __restrict__ partials,     // d_ws: ITEMS floats, one per wave
    float* __restrict__ sm_m1)        // out + NMASK (= smoothed base - 1, 16B-aligned)
{
    const int wave = threadIdx.x >> 6;
    const int lane = threadIdx.x & 63;

    // XCD-aware bijective swizzle (NBLK = 792 = 8*99): contiguous 99-block
    // range per XCD -> vertically adjacent chunks share halo rows in one L2.
    const int bid  = blockIdx.x;
    const int sw   = (bid & 7) * (NBLK / 8) + (bid >> 3);
    const int item = sw * 4 + wave;

    const int img   = item / (NSTRIP * NCHUNK);
    const int rem   = item % (NSTRIP * NCHUNK);
    const int strip = rem / NCHUNK;
    const int chunk = rem % NCHUNK;

    const int hA = chunk * CH;
    const int iq = strip * 62 - 1 + lane;
    const bool colsafe = (unsigned)iq < (unsigned)NQ;      // loop-invariant
    const bool outlane = (lane >= 1) && (lane <= 62) && colsafe;
    const bool lead    = outlane && (iq > 0);
    const bool ego     = (img % L_) == 0;

    const float* xb = x + (size_t)img * (2 * HW_);
    const size_t obase = (size_t)img * HW_;

    // Exact separable weights: g2d[i][j] == u[i] * hv[j]
    Wt w;
    {
        const float g12 = gw[12];
        w.u0 = gw[2];  w.u1 = gw[7];  w.u2 = gw[12]; w.u3 = gw[17]; w.u4 = gw[22];
        w.v0 = gw[10] / g12; w.v1 = gw[11] / g12; w.v2 = gw[12] / g12;
        w.v3 = gw[13] / g12; w.v4 = gw[14] / g12;
    }

    // Interior chunks (1..NCHUNK-2) never touch OOB rows -> skip the h check.
    float cnt;
    if (chunk == 0 || chunk == NCHUNK - 1)
        cnt = run_chunk<true >(xb, w, hA, iq, colsafe, outlane, lead, ego, obase, out_mask, sm_m1);
    else
        cnt = run_chunk<false>(xb, w, hA, iq, colsafe, outlane, lead, ego, obase, out_mask, sm_m1);

    // Per-wave reduce -> unique d_ws slot. NO atomics anywhere.
    #pragma unroll
    for (int off = 32; off >= 1; off >>= 1)
        cnt += __shfl_down(cnt, off);
    if (lane == 0)
        partials[item] = cnt;
}

// Tiny second kernel: reduce ITEMS partials -> rate scalar (single block)
__global__ __launch_bounds__(256) void comm_rate_reduce(
    const float* __restrict__ partials, float* __restrict__ rate)
{
    float s = 0.f;
    for (int i = threadIdx.x; i < ITEMS; i += 256)
        s += partials[i];
    #pragma unroll
    for (int off = 32; off >= 1; off >>= 1)
        s += __shfl_down(s, off);
    __shared__ float ws[4];
    if ((threadIdx.x & 63) == 0) ws[threadIdx.x >> 6] = s;
    __syncthreads();
    if (threadIdx.x == 0)
        rate[0] = (ws[0] + ws[1] + ws[2] + ws[3]) * (1.f / (float)NMASK);
}

extern "C" void kernel_launch(void* const* d_in, const int* in_sizes, int n_in,
                              void* d_out, int out_size, void* d_ws, size_t ws_size,
                              hipStream_t stream) {
    const float* x  = (const float*)d_in[0];
    const float* gw = (const float*)d_in[1];
    float* out      = (float*)d_out;

    float* mask_out = out;               // 23,789,568
    float* rate_out = out + NMASK;       // 1
    float* sm_m1    = out + NMASK;       // smoothed base - 1 (16B-aligned)
    float* partials = (float*)d_ws;      // ITEMS floats of scratch

    // rate slot (= sm_m1[0]) is written ONLY by comm_rate_reduce; smoothed
    // stores never touch it (f4 stores start at idx>=4; scalar path >= sm_m1+1).
    dim3 grid(NBLK, 1, 1);               // 792 blocks x 256 threads = 3168 waves
    dim3 block(256, 1, 1);
    comm_fused_v15<<<grid, block, 0, stream>>>(x, gw, mask_out, partials, sm_m1);
    comm_rate_reduce<<<1, 256, 0, stream>>>(partials, rate_out);
}